// Round 1
// baseline (321.920 us; speedup 1.0000x reference)
//
#include <hip/hip_runtime.h>
#include <hip/hip_cooperative_groups.h>

namespace cg = cooperative_groups;

#define NROW 512
#define NCOL 65536

static __device__ __forceinline__ float wave_sum(float x) {
  #pragma unroll
  for (int off = 32; off; off >>= 1) x += __shfl_down(x, off, 64);
  return x;
}

// One cooperative kernel: 256 blocks x 1024 threads (1 block/CU, 16 waves/CU).
// Phase A: v1 = b/(colsum(E)/512+eps)        [block owns 256-col slab, all rows]
// Phase B: u1 = a/(E v1+eps) + loss partial  [block owns 2 contiguous rows]
// Phase C: t = colsum(E^T u1), err1          [col slab again; t stays in regs]
// converged -> out = 100*loss ; else -> k5-style fallback loop (iters 2..100)
__global__ __launch_bounds__(1024)
void sinkhorn_all(const float* __restrict__ M, float* __restrict__ out,
                  float* __restrict__ v, float* __restrict__ u,
                  float* __restrict__ eA) {
  cg::grid_group grid = cg::this_grid();
  const int tid = threadIdx.x, bid = blockIdx.x;
  const float am = 1.0f / NROW, bm = 1.0f / NCOL, EPSV = 1e-16f;

  __shared__ float sCol[16 * 256];
  __shared__ float sU[NROW];
  __shared__ float sRedA[16], sRedB[16], sRedC[16], sRedD[16];

  const int chunk = tid & 63;          // 64 float4 chunks = 256 cols per block
  const int part  = tid >> 6;          // 16 waves x 32 rows each
  const int col0  = (bid << 8) + (chunk << 2);
  const int r0    = part << 5;
  const int row0  = bid << 1;

  if (bid == 0 && tid < 4) eA[tid] = 0.f;  // [0]=err1 [1]=err51 [2]=loss1

  // ---- Phase A: colsum(E) for this block's 256 cols -> v slice -------------
  {
    const float* Mp = M + (size_t)r0 * NCOL + col0;
    float4 cs = {0.f, 0.f, 0.f, 0.f};
    #pragma unroll 8
    for (int rr = 0; rr < 32; ++rr) {
      float4 m = *(const float4*)(Mp + (size_t)rr * NCOL);
      cs.x += __expf(-20.f * m.x);
      cs.y += __expf(-20.f * m.y);
      cs.z += __expf(-20.f * m.z);
      cs.w += __expf(-20.f * m.w);
    }
    *(float4*)(sCol + part * 256 + (chunk << 2)) = cs;
    __syncthreads();
    if (tid < 256) {
      float t = 0.f;
      #pragma unroll
      for (int p = 0; p < 16; ++p) t += sCol[p * 256 + tid];
      v[(bid << 8) + tid] = bm / (t * am + EPSV);
    }
  }
  grid.sync();

  // ---- Phase B: row dots (u1) + fused loss partial s_i ---------------------
  {
    const float4* M40 = (const float4*)M + (size_t)row0 * (NCOL / 4);
    const float4* M41 = M40 + (NCOL / 4);
    const float4* V4  = (const float4*)v;
    float ra = 0.f, rb = 0.f, sa = 0.f, sb = 0.f;
    #pragma unroll 4
    for (int it = 0; it < NCOL / 4 / 1024; ++it) {   // 16 iters
      const int c = (it << 10) + tid;
      float4 vv = V4[c];
      float4 m0 = M40[c], m1 = M41[c];
      float e;
      e = __expf(-20.f * m0.x); ra = fmaf(e, vv.x, ra); sa = fmaf(e * m0.x, vv.x, sa);
      e = __expf(-20.f * m0.y); ra = fmaf(e, vv.y, ra); sa = fmaf(e * m0.y, vv.y, sa);
      e = __expf(-20.f * m0.z); ra = fmaf(e, vv.z, ra); sa = fmaf(e * m0.z, vv.z, sa);
      e = __expf(-20.f * m0.w); ra = fmaf(e, vv.w, ra); sa = fmaf(e * m0.w, vv.w, sa);
      e = __expf(-20.f * m1.x); rb = fmaf(e, vv.x, rb); sb = fmaf(e * m1.x, vv.x, sb);
      e = __expf(-20.f * m1.y); rb = fmaf(e, vv.y, rb); sb = fmaf(e * m1.y, vv.y, sb);
      e = __expf(-20.f * m1.z); rb = fmaf(e, vv.z, rb); sb = fmaf(e * m1.z, vv.z, sb);
      e = __expf(-20.f * m1.w); rb = fmaf(e, vv.w, rb); sb = fmaf(e * m1.w, vv.w, sb);
    }
    ra = wave_sum(ra); rb = wave_sum(rb);
    sa = wave_sum(sa); sb = wave_sum(sb);
    if ((tid & 63) == 0) {
      sRedA[tid >> 6] = ra; sRedB[tid >> 6] = rb;
      sRedC[tid >> 6] = sa; sRedD[tid >> 6] = sb;
    }
    __syncthreads();
    if (tid == 0) {
      float rs0 = 0.f, rs1 = 0.f, ss0 = 0.f, ss1 = 0.f;
      #pragma unroll
      for (int w = 0; w < 16; ++w) {
        rs0 += sRedA[w]; rs1 += sRedB[w];
        ss0 += sRedC[w]; ss1 += sRedD[w];
      }
      float u0v = am / (rs0 + EPSV);
      float u1v = am / (rs1 + EPSV);
      u[row0] = u0v; u[row0 + 1] = u1v;
      atomicAdd(&eA[2], u0v * ss0 + u1v * ss1);   // loss partial
    }
  }
  grid.sync();

  // ---- Phase C: t = colsum(E^T u1) (kept in regs), err1 --------------------
  float tt = 0.f;
  {
    if (tid < NROW) sU[tid] = u[tid];
    __syncthreads();
    const float* Mp = M + (size_t)r0 * NCOL + col0;
    float4 cs = {0.f, 0.f, 0.f, 0.f};
    #pragma unroll 8
    for (int rr = 0; rr < 32; ++rr) {
      float4 m = *(const float4*)(Mp + (size_t)rr * NCOL);
      float us = sU[r0 + rr];
      cs.x = fmaf(__expf(-20.f * m.x), us, cs.x);
      cs.y = fmaf(__expf(-20.f * m.y), us, cs.y);
      cs.z = fmaf(__expf(-20.f * m.z), us, cs.z);
      cs.w = fmaf(__expf(-20.f * m.w), us, cs.w);
    }
    *(float4*)(sCol + part * 256 + (chunk << 2)) = cs;
    __syncthreads();
    float pe = 0.f;
    if (tid < 256) {
      #pragma unroll
      for (int p = 0; p < 16; ++p) tt += sCol[p * 256 + tid];
      pe = fabsf(v[(bid << 8) + tid] * tt - bm);
    }
    pe = wave_sum(pe);
    if ((tid & 63) == 0) sRedA[tid >> 6] = pe;
    __syncthreads();
    if (tid == 0) {
      float s = 0.f;
      #pragma unroll
      for (int w = 0; w < 16; ++w) s += sRedA[w];
      atomicAdd(&eA[0], s);
    }
  }
  grid.sync();

  // ---- decide --------------------------------------------------------------
  if (eA[0] <= 0.005f) {
    if (bid == 0 && tid == 0) out[0] = 100.f * eA[2];
    return;
  }

  // ---- fallback: iters 2..100 (k5 logic, same buffers, tt live in regs) ----
  if (bid == 0 && tid == 0) out[0] = 0.f;
  int cpt = 1;
  while (true) {
    if (tid < 256) v[(bid << 8) + tid] = bm / (tt + EPSV);
    grid.sync();
    cpt++;
    {
      const float4* M40 = (const float4*)M + (size_t)row0 * (NCOL / 4);
      const float4* M41 = M40 + (NCOL / 4);
      const float4* V4  = (const float4*)v;
      float ra = 0.f, rb = 0.f;
      #pragma unroll 4
      for (int it = 0; it < NCOL / 4 / 1024; ++it) {
        const int c = (it << 10) + tid;
        float4 vv = V4[c];
        float4 m0 = M40[c], m1 = M41[c];
        ra += __expf(-20.f * m0.x) * vv.x + __expf(-20.f * m0.y) * vv.y
            + __expf(-20.f * m0.z) * vv.z + __expf(-20.f * m0.w) * vv.w;
        rb += __expf(-20.f * m1.x) * vv.x + __expf(-20.f * m1.y) * vv.y
            + __expf(-20.f * m1.z) * vv.z + __expf(-20.f * m1.w) * vv.w;
      }
      ra = wave_sum(ra); rb = wave_sum(rb);
      if ((tid & 63) == 0) { sRedA[tid >> 6] = ra; sRedB[tid >> 6] = rb; }
      __syncthreads();
      if (tid == 0) {
        float s0 = 0.f, s1 = 0.f;
        #pragma unroll
        for (int w = 0; w < 16; ++w) { s0 += sRedA[w]; s1 += sRedB[w]; }
        u[row0]     = am / (s0 + EPSV);
        u[row0 + 1] = am / (s1 + EPSV);
      }
    }
    grid.sync();
    if (cpt >= 100) break;

    if (tid < NROW) sU[tid] = u[tid];
    __syncthreads();
    {
      const float* Mp = M + (size_t)r0 * NCOL + col0;
      float4 cs = {0.f, 0.f, 0.f, 0.f};
      #pragma unroll 4
      for (int rr = 0; rr < 32; ++rr) {
        float4 m = *(const float4*)(Mp + (size_t)rr * NCOL);
        float us = sU[r0 + rr];
        cs.x = fmaf(__expf(-20.f * m.x), us, cs.x);
        cs.y = fmaf(__expf(-20.f * m.y), us, cs.y);
        cs.z = fmaf(__expf(-20.f * m.z), us, cs.z);
        cs.w = fmaf(__expf(-20.f * m.w), us, cs.w);
      }
      *(float4*)(sCol + part * 256 + (chunk << 2)) = cs;
      __syncthreads();
      if (tid < 256) {
        tt = 0.f;
        #pragma unroll
        for (int p = 0; p < 16; ++p) tt += sCol[p * 256 + tid];
      }
    }
    if (cpt == 51) {
      float pe = (tid < 256) ? fabsf(v[(bid << 8) + tid] * tt - bm) : 0.f;
      pe = wave_sum(pe);
      if ((tid & 63) == 0) sRedA[tid >> 6] = pe;
      __syncthreads();
      if (tid == 0) {
        float s = 0.f;
        #pragma unroll
        for (int w = 0; w < 16; ++w) s += sRedA[w];
        atomicAdd(&eA[1], s);
      }
      grid.sync();
      if (eA[1] <= 0.005f) break;
    }
  }

  // final loss with current u, v
  __syncthreads();
  if (tid < NROW) sU[tid] = u[tid];
  __syncthreads();
  {
    const float4 vv = *(const float4*)(v + col0);
    const float* Mp = M + (size_t)r0 * NCOL + col0;
    float lacc = 0.f;
    #pragma unroll 4
    for (int rr = 0; rr < 32; ++rr) {
      float4 m = *(const float4*)(Mp + (size_t)rr * NCOL);
      float us = sU[r0 + rr];
      lacc += us * (__expf(-20.f * m.x) * m.x * vv.x
                  + __expf(-20.f * m.y) * m.y * vv.y
                  + __expf(-20.f * m.z) * m.z * vv.z
                  + __expf(-20.f * m.w) * m.w * vv.w);
    }
    lacc = wave_sum(lacc);
    if ((tid & 63) == 0) sRedA[tid >> 6] = lacc;
    __syncthreads();
    if (tid == 0) {
      float s = 0.f;
      #pragma unroll
      for (int w = 0; w < 16; ++w) s += sRedA[w];
      atomicAdd(out, 100.f * s);
    }
  }
}

extern "C" void kernel_launch(void* const* d_in, const int* in_sizes, int n_in,
                              void* d_out, int out_size, void* d_ws, size_t ws_size,
                              hipStream_t stream) {
  const float* M = (const float*)d_in[0];
  float* out = (float*)d_out;

  // ws: v (256 KB) | u (4 KB pad) | eA (256 B)
  const size_t offV = 0;
  const size_t offU = offV + (size_t)NCOL * sizeof(float);
  const size_t offE = offU + 4096;
  const size_t need = offE + 256;
  if (ws_size < need) return;

  char* ws = (char*)d_ws;
  float* v  = (float*)(ws + offV);
  float* u  = (float*)(ws + offU);
  float* eA = (float*)(ws + offE);

  void* args[] = { (void*)&M, (void*)&out, (void*)&v, (void*)&u, (void*)&eA };
  hipLaunchCooperativeKernel((void*)sinkhorn_all, dim3(256), dim3(1024),
                             args, 0, stream);
}

// Round 2
// 308.131 us; speedup vs baseline: 1.0448x; 1.0448x over previous
//
#include <hip/hip_runtime.h>
#include <hip/hip_cooperative_groups.h>

namespace cg = cooperative_groups;

#define NROW 512
#define NCOL 65536
#define BANDS 8

static __device__ __forceinline__ float wave_sum(float x) {
  #pragma unroll
  for (int off = 32; off; off >>= 1) x += __shfl_down(x, off, 64);
  return x;
}

// ---- k1: streaming partial colsums of E = exp(-20M) ------------------------
// 2048 blocks x 256 thr (8 blocks/CU, 32 waves/CU). Block (band, colblk):
// rows [band*64, +64), cols [colblk*256, +256). Thread: 4 cols x 16 rows.
__global__ __launch_bounds__(256, 8)
void k1_partial(const float* __restrict__ M, float* __restrict__ tPart,
                float* __restrict__ eA) {
  const int tid = threadIdx.x, bid = blockIdx.x;
  const int colblk = bid & 255, band = bid >> 8;
  const int chunk = tid & 63;            // 64 float4 chunks = 256 cols
  const int part  = tid >> 6;            // 4 parts x 16 rows
  const int col0  = (colblk << 8) + (chunk << 2);
  const int r0    = (band << 6) + (part << 4);

  __shared__ float sCol[4 * 256];

  if (bid == 0 && tid < 4) eA[tid] = 0.f;  // [0]=err1 [1]=err51 [2]=loss

  const float* Mp = M + (size_t)r0 * NCOL + col0;
  float4 cs = {0.f, 0.f, 0.f, 0.f};
  #pragma unroll 8
  for (int rr = 0; rr < 16; ++rr) {
    float4 m = *(const float4*)(Mp + (size_t)rr * NCOL);
    cs.x += __expf(-20.f * m.x);
    cs.y += __expf(-20.f * m.y);
    cs.z += __expf(-20.f * m.z);
    cs.w += __expf(-20.f * m.w);
  }
  *(float4*)(sCol + part * 256 + (chunk << 2)) = cs;
  __syncthreads();
  if (tid < 64) {
    float4 a = *(const float4*)(sCol + (tid << 2));
    float4 b = *(const float4*)(sCol + 256 + (tid << 2));
    float4 c = *(const float4*)(sCol + 512 + (tid << 2));
    float4 d = *(const float4*)(sCol + 768 + (tid << 2));
    float4 t = {a.x + b.x + c.x + d.x, a.y + b.y + c.y + d.y,
                a.z + b.z + c.z + d.z, a.w + b.w + c.w + d.w};
    *(float4*)(tPart + (size_t)band * NCOL + (colblk << 8) + (tid << 2)) = t;
  }
}

// ---- k1b: v1 = b / (colsum/512 + eps) --------------------------------------
__global__ __launch_bounds__(256)
void k1b_v1(const float* __restrict__ tPart, float* __restrict__ v) {
  const int gid = blockIdx.x * 256 + threadIdx.x;
  const int col0 = gid << 2;
  const float am = 1.0f / NROW, bm = 1.0f / NCOL, EPSV = 1e-16f;
  float4 t = {0.f, 0.f, 0.f, 0.f};
  #pragma unroll
  for (int b = 0; b < BANDS; ++b) {
    float4 p = *(const float4*)(tPart + (size_t)b * NCOL + col0);
    t.x += p.x; t.y += p.y; t.z += p.z; t.w += p.w;
  }
  float4 vv = {bm / (t.x * am + EPSV), bm / (t.y * am + EPSV),
               bm / (t.z * am + EPSV), bm / (t.w * am + EPSV)};
  *(float4*)(v + col0) = vv;
}

// ---- k2: u1[row] = a / (E[row,:] . v + eps) --------------------------------
// 512 blocks x 1024 thr (2 blocks/CU, 32 waves/CU); one row per block.
__global__ __launch_bounds__(1024, 8)
void k2_rowdot(const float* __restrict__ M, const float* __restrict__ v,
               float* __restrict__ u) {
  const int tid = threadIdx.x, row = blockIdx.x;
  const float am = 1.0f / NROW, EPSV = 1e-16f;
  const float4* M4 = (const float4*)M + (size_t)row * (NCOL / 4);
  const float4* V4 = (const float4*)v;
  __shared__ float sRed[16];

  float acc = 0.f;
  #pragma unroll 8
  for (int it = 0; it < NCOL / 4 / 1024; ++it) {   // 16 iters
    const int c = (it << 10) + tid;
    float4 m = M4[c];
    float4 vv = V4[c];
    acc += __expf(-20.f * m.x) * vv.x + __expf(-20.f * m.y) * vv.y
         + __expf(-20.f * m.z) * vv.z + __expf(-20.f * m.w) * vv.w;
  }
  acc = wave_sum(acc);
  if ((tid & 63) == 0) sRed[tid >> 6] = acc;
  __syncthreads();
  if (tid == 0) {
    float s = 0.f;
    #pragma unroll
    for (int w = 0; w < 16; ++w) s += sRed[w];
    u[row] = am / (s + EPSV);
  }
}

// ---- k3a: streaming partial colsums of E^T u1 + fused loss ----------------
// Same geometry as k1.
__global__ __launch_bounds__(256, 8)
void k3a_partial(const float* __restrict__ M, const float* __restrict__ v,
                 const float* __restrict__ u, float* __restrict__ tPart,
                 float* __restrict__ eA) {
  const int tid = threadIdx.x, bid = blockIdx.x;
  const int colblk = bid & 255, band = bid >> 8;
  const int chunk = tid & 63;
  const int part  = tid >> 6;
  const int col0  = (colblk << 8) + (chunk << 2);
  const int r0l   = part << 4;               // local row offset in band

  __shared__ float sU[64];
  __shared__ float sCol[4 * 256];
  __shared__ float sRed[4];

  if (tid < 64) sU[tid] = u[(band << 6) + tid];
  __syncthreads();

  const float4 vv = *(const float4*)(v + col0);
  const float* Mp = M + (size_t)((band << 6) + r0l) * NCOL + col0;
  float4 cs = {0.f, 0.f, 0.f, 0.f};
  float lacc = 0.f;
  #pragma unroll 8
  for (int rr = 0; rr < 16; ++rr) {
    float4 m = *(const float4*)(Mp + (size_t)rr * NCOL);
    float e0 = __expf(-20.f * m.x), e1 = __expf(-20.f * m.y);
    float e2 = __expf(-20.f * m.z), e3 = __expf(-20.f * m.w);
    float us = sU[r0l + rr];
    cs.x = fmaf(e0, us, cs.x);
    cs.y = fmaf(e1, us, cs.y);
    cs.z = fmaf(e2, us, cs.z);
    cs.w = fmaf(e3, us, cs.w);
    lacc += us * (e0 * m.x * vv.x + e1 * m.y * vv.y
                + e2 * m.z * vv.z + e3 * m.w * vv.w);
  }
  *(float4*)(sCol + part * 256 + (chunk << 2)) = cs;
  lacc = wave_sum(lacc);
  if ((tid & 63) == 0) sRed[tid >> 6] = lacc;
  __syncthreads();
  if (tid < 64) {
    float4 a = *(const float4*)(sCol + (tid << 2));
    float4 b = *(const float4*)(sCol + 256 + (tid << 2));
    float4 c = *(const float4*)(sCol + 512 + (tid << 2));
    float4 d = *(const float4*)(sCol + 768 + (tid << 2));
    float4 t = {a.x + b.x + c.x + d.x, a.y + b.y + c.y + d.y,
                a.z + b.z + c.z + d.z, a.w + b.w + c.w + d.w};
    *(float4*)(tPart + (size_t)band * NCOL + (colblk << 8) + (tid << 2)) = t;
  }
  if (tid == 0)
    atomicAdd(&eA[2], sRed[0] + sRed[1] + sRed[2] + sRed[3]);
}

// ---- k3b: t = reduce(partials) (stored for k5), err = sum|v*t - b| --------
__global__ __launch_bounds__(256)
void k3b_err(const float* __restrict__ tPart, const float* __restrict__ v,
             float* __restrict__ tArr, float* __restrict__ eA) {
  const int tid = threadIdx.x;
  const int gid = blockIdx.x * 256 + tid;
  const int col0 = gid << 2;
  const float bm = 1.0f / NCOL;
  __shared__ float sRed[4];

  float4 t = {0.f, 0.f, 0.f, 0.f};
  #pragma unroll
  for (int b = 0; b < BANDS; ++b) {
    float4 p = *(const float4*)(tPart + (size_t)b * NCOL + col0);
    t.x += p.x; t.y += p.y; t.z += p.z; t.w += p.w;
  }
  *(float4*)(tArr + col0) = t;
  float4 vv = *(const float4*)(v + col0);
  float pe = fabsf(vv.x * t.x - bm) + fabsf(vv.y * t.y - bm)
           + fabsf(vv.z * t.z - bm) + fabsf(vv.w * t.w - bm);
  pe = wave_sum(pe);
  if ((tid & 63) == 0) sRed[tid >> 6] = pe;
  __syncthreads();
  if (tid == 0)
    atomicAdd(&eA[0], sRed[0] + sRed[1] + sRed[2] + sRed[3]);
}

// ---- k4: decide ------------------------------------------------------------
__global__ void k4_decide(const float* __restrict__ eA, float* __restrict__ out,
                          int* __restrict__ done) {
  if (threadIdx.x == 0) {
    if (eA[0] <= 0.005f) { out[0] = 100.f * eA[2]; done[0] = 1; }
    else                 { out[0] = 0.f;           done[0] = 0; }
  }
}

// ---- k5: cooperative fallback (iters 2..100 + loss); exits when done -------
__global__ __launch_bounds__(1024)
void k5_fallback(const float* __restrict__ M, float* __restrict__ out,
                 float* __restrict__ v, float* __restrict__ u,
                 const float* __restrict__ tArr, float* __restrict__ eA,
                 const int* __restrict__ done) {
  if (done[0]) return;
  cg::grid_group grid = cg::this_grid();
  const int tid = threadIdx.x, bid = blockIdx.x;
  const float am = 1.0f / NROW, bm = 1.0f / NCOL, EPSV = 1e-16f;

  __shared__ float sU[NROW];
  __shared__ float sCol[16 * 256];
  __shared__ float sRedA[16], sRedB[16];

  const int chunk = tid & 63;
  const int part  = tid >> 6;
  const int col0  = (bid << 8) + (chunk << 2);
  const int r0    = part << 5;
  const int row0  = bid << 1;

  float tt = (tid < 256) ? tArr[(bid << 8) + tid] : 0.f;

  int cpt = 1;
  while (true) {
    if (tid < 256) v[(bid << 8) + tid] = bm / (tt + EPSV);
    grid.sync();
    cpt++;

    {
      const float4* M40 = (const float4*)M + (size_t)row0 * (NCOL / 4);
      const float4* M41 = (const float4*)M + (size_t)(row0 + 1) * (NCOL / 4);
      const float4* V4  = (const float4*)v;
      float ra = 0.f, rb = 0.f;
      #pragma unroll 4
      for (int it = 0; it < NCOL / 4 / 1024; ++it) {
        const int c = (it << 10) + tid;
        float4 vv = V4[c];
        float4 m0 = M40[c], m1 = M41[c];
        ra += __expf(-20.f * m0.x) * vv.x + __expf(-20.f * m0.y) * vv.y
            + __expf(-20.f * m0.z) * vv.z + __expf(-20.f * m0.w) * vv.w;
        rb += __expf(-20.f * m1.x) * vv.x + __expf(-20.f * m1.y) * vv.y
            + __expf(-20.f * m1.z) * vv.z + __expf(-20.f * m1.w) * vv.w;
      }
      ra = wave_sum(ra); rb = wave_sum(rb);
      if ((tid & 63) == 0) { sRedA[tid >> 6] = ra; sRedB[tid >> 6] = rb; }
      __syncthreads();
      if (tid < 2) {
        const float* sr = (tid == 0) ? sRedA : sRedB;
        float s = 0.f;
        #pragma unroll
        for (int w = 0; w < 16; ++w) s += sr[w];
        u[row0 + tid] = am / (s + EPSV);
      }
    }
    grid.sync();
    if (cpt >= 100) break;

    if (tid < NROW) sU[tid] = u[tid];
    __syncthreads();
    float4 cs = {0.f, 0.f, 0.f, 0.f};
    #pragma unroll 4
    for (int r = r0; r < r0 + 32; ++r) {
      float4 m = *(const float4*)(M + (size_t)r * NCOL + col0);
      float us = sU[r];
      cs.x = fmaf(__expf(-20.f * m.x), us, cs.x);
      cs.y = fmaf(__expf(-20.f * m.y), us, cs.y);
      cs.z = fmaf(__expf(-20.f * m.z), us, cs.z);
      cs.w = fmaf(__expf(-20.f * m.w), us, cs.w);
    }
    *(float4*)(sCol + part * 256 + (chunk << 2)) = cs;
    __syncthreads();
    if (tid < 256) {
      tt = 0.f;
      #pragma unroll
      for (int p = 0; p < 16; ++p) tt += sCol[p * 256 + tid];
    }

    if (cpt == 51) {
      float pe = (tid < 256) ? fabsf(v[(bid << 8) + tid] * tt - bm) : 0.f;
      pe = wave_sum(pe);
      __syncthreads();
      if ((tid & 63) == 0) sRedA[tid >> 6] = pe;
      __syncthreads();
      if (tid == 0) {
        float s = 0.f;
        #pragma unroll
        for (int w = 0; w < 16; ++w) s += sRedA[w];
        atomicAdd(&eA[1], s);
      }
      grid.sync();
      if (eA[1] <= 0.005f) break;
    }
  }

  __syncthreads();
  if (tid < NROW) sU[tid] = u[tid];
  __syncthreads();
  {
    const float4 vv = *(const float4*)(v + col0);
    float lacc = 0.f;
    #pragma unroll 4
    for (int r = r0; r < r0 + 32; ++r) {
      float4 m = *(const float4*)(M + (size_t)r * NCOL + col0);
      float us = sU[r];
      lacc += us * (__expf(-20.f * m.x) * m.x * vv.x
                  + __expf(-20.f * m.y) * m.y * vv.y
                  + __expf(-20.f * m.z) * m.z * vv.z
                  + __expf(-20.f * m.w) * m.w * vv.w);
    }
    lacc = wave_sum(lacc);
    if ((tid & 63) == 0) sRedA[tid >> 6] = lacc;
    __syncthreads();
    if (tid == 0) {
      float s = 0.f;
      #pragma unroll
      for (int w = 0; w < 16; ++w) s += sRedA[w];
      atomicAdd(out, 100.f * s);
    }
  }
}

extern "C" void kernel_launch(void* const* d_in, const int* in_sizes, int n_in,
                              void* d_out, int out_size, void* d_ws, size_t ws_size,
                              hipStream_t stream) {
  const float* M = (const float*)d_in[0];
  float* out = (float*)d_out;

  // ws: v | tArr | u | eA | done | tPart
  const size_t offV = 0;
  const size_t offT = offV + (size_t)NCOL * sizeof(float);      // 256 KB
  const size_t offU = offT + (size_t)NCOL * sizeof(float);      // 256 KB
  const size_t offE = offU + 4096;
  const size_t offD = offE + 256;
  const size_t offP = offD + 256;
  const size_t need = offP + (size_t)BANDS * NCOL * sizeof(float); // +2 MB
  if (ws_size < need) return;

  char* ws = (char*)d_ws;
  float* v     = (float*)(ws + offV);
  float* tArr  = (float*)(ws + offT);
  float* u     = (float*)(ws + offU);
  float* eA    = (float*)(ws + offE);
  int*   done  = (int*)(ws + offD);
  float* tPart = (float*)(ws + offP);

  k1_partial <<<dim3(2048), dim3(256),  0, stream>>>(M, tPart, eA);
  k1b_v1     <<<dim3(64),   dim3(256),  0, stream>>>(tPart, v);
  k2_rowdot  <<<dim3(512),  dim3(1024), 0, stream>>>(M, v, u);
  k3a_partial<<<dim3(2048), dim3(256),  0, stream>>>(M, v, u, tPart, eA);
  k3b_err    <<<dim3(64),   dim3(256),  0, stream>>>(tPart, v, tArr, eA);
  k4_decide  <<<dim3(1),    dim3(64),   0, stream>>>(eA, out, done);

  void* args[] = { (void*)&M, (void*)&out, (void*)&v, (void*)&u,
                   (void*)&tArr, (void*)&eA, (void*)&done };
  hipLaunchCooperativeKernel((void*)k5_fallback, dim3(256), dim3(1024),
                             args, 0, stream);
}

// Round 3
// 275.891 us; speedup vs baseline: 1.1668x; 1.1169x over previous
//
#include <hip/hip_runtime.h>
#include <hip/hip_cooperative_groups.h>

namespace cg = cooperative_groups;

#define NROW 512
#define NCOL 65536

static __device__ __forceinline__ float wave_sum(float x) {
  #pragma unroll
  for (int off = 32; off; off >>= 1) x += __shfl_down(x, off, 64);
  return x;
}

// ---- k1: v1 = b/(colsum(E)/512+eps), one kernel, no intermediates ----------
// 512 blocks x 512 thr (2 blk/CU, 16 waves/CU). Block owns 128 cols, all rows.
// Thread: 4 cols x 32 rows (same pattern as the proven round-0 kernel).
__global__ __launch_bounds__(512)
void k1_colsum(const float* __restrict__ M, float* __restrict__ v,
               float* __restrict__ eA) {
  const int tid = threadIdx.x, bid = blockIdx.x;
  const int chunk = tid & 31;           // 32 float4 chunks = 128 cols
  const int part  = tid >> 5;           // 16 parts x 32 rows
  const int col0  = (bid << 7) + (chunk << 2);
  const int r0    = part << 5;
  const float am = 1.0f / NROW, bm = 1.0f / NCOL, EPSV = 1e-16f;

  __shared__ float sCol[16 * 128];

  if (bid == 0 && tid < 8) eA[tid] = 0.f;  // [0]=err1 [1]=err51 [2]=loss [4]=cnt

  const float* Mp = M + (size_t)r0 * NCOL + col0;
  float4 cs = {0.f, 0.f, 0.f, 0.f};
  #pragma unroll 8
  for (int rr = 0; rr < 32; ++rr) {
    float4 m = *(const float4*)(Mp + (size_t)rr * NCOL);
    cs.x += __expf(-20.f * m.x);
    cs.y += __expf(-20.f * m.y);
    cs.z += __expf(-20.f * m.z);
    cs.w += __expf(-20.f * m.w);
  }
  *(float4*)(sCol + part * 128 + (chunk << 2)) = cs;
  __syncthreads();
  if (tid < 128) {
    float t = 0.f;
    #pragma unroll
    for (int p = 0; p < 16; ++p) t += sCol[p * 128 + tid];
    v[(bid << 7) + tid] = bm / (t * am + EPSV);
  }
}

// ---- k2: u1[row] = a / (E[row,:] . v + eps) --------------------------------
// 512 blocks x 512 thr; one contiguous row per block.
__global__ __launch_bounds__(512)
void k2_rowdot(const float* __restrict__ M, const float* __restrict__ v,
               float* __restrict__ u) {
  const int tid = threadIdx.x, row = blockIdx.x;
  const float am = 1.0f / NROW, EPSV = 1e-16f;
  const float4* M4 = (const float4*)M + (size_t)row * (NCOL / 4);
  const float4* V4 = (const float4*)v;
  __shared__ float sRed[8];

  float acc = 0.f;
  #pragma unroll 8
  for (int it = 0; it < NCOL / 4 / 512; ++it) {   // 32 iters
    const int c = (it << 9) + tid;
    float4 m = M4[c];
    float4 vv = V4[c];
    acc += __expf(-20.f * m.x) * vv.x + __expf(-20.f * m.y) * vv.y
         + __expf(-20.f * m.z) * vv.z + __expf(-20.f * m.w) * vv.w;
  }
  acc = wave_sum(acc);
  if ((tid & 63) == 0) sRed[tid >> 6] = acc;
  __syncthreads();
  if (tid == 0) {
    float s = 0.f;
    #pragma unroll
    for (int w = 0; w < 8; ++w) s += sRed[w];
    u[row] = am / (s + EPSV);
  }
}

// ---- k3: t=colsum(E^T u1), err1, loss, tArr, + last-block decide ----------
// Same geometry as k1. Replaces old k3a + k3b + k4 (3 kernels -> 1).
__global__ __launch_bounds__(512)
void k3_colsum_u(const float* __restrict__ M, const float* __restrict__ v,
                 const float* __restrict__ u, float* __restrict__ tArr,
                 float* __restrict__ eA, float* __restrict__ out,
                 int* __restrict__ done) {
  const int tid = threadIdx.x, bid = blockIdx.x;
  const int chunk = tid & 31;
  const int part  = tid >> 5;
  const int col0  = (bid << 7) + (chunk << 2);
  const int r0    = part << 5;
  const float bm = 1.0f / NCOL;

  __shared__ float sU[NROW];
  __shared__ float sCol[16 * 128];
  __shared__ float sRed[8];

  sU[tid] = u[tid];                       // 512 threads == 512 rows
  __syncthreads();

  const float4 vv = *(const float4*)(v + col0);
  const float* Mp = M + (size_t)r0 * NCOL + col0;
  float4 cs = {0.f, 0.f, 0.f, 0.f};
  float lacc = 0.f;
  #pragma unroll 8
  for (int rr = 0; rr < 32; ++rr) {
    float4 m = *(const float4*)(Mp + (size_t)rr * NCOL);
    float e0 = __expf(-20.f * m.x), e1 = __expf(-20.f * m.y);
    float e2 = __expf(-20.f * m.z), e3 = __expf(-20.f * m.w);
    float us = sU[r0 + rr];
    cs.x = fmaf(e0, us, cs.x);
    cs.y = fmaf(e1, us, cs.y);
    cs.z = fmaf(e2, us, cs.z);
    cs.w = fmaf(e3, us, cs.w);
    lacc += us * (e0 * m.x * vv.x + e1 * m.y * vv.y
                + e2 * m.z * vv.z + e3 * m.w * vv.w);
  }
  *(float4*)(sCol + part * 128 + (chunk << 2)) = cs;
  lacc = wave_sum(lacc);
  if ((tid & 63) == 0) sRed[tid >> 6] = lacc;
  __syncthreads();

  float lblk = 0.f;
  if (tid == 0) {
    #pragma unroll
    for (int w = 0; w < 8; ++w) lblk += sRed[w];
  }
  float pe = 0.f;
  if (tid < 128) {
    float t = 0.f;
    #pragma unroll
    for (int p = 0; p < 16; ++p) t += sCol[p * 128 + tid];
    tArr[(bid << 7) + tid] = t;
    pe = fabsf(v[(bid << 7) + tid] * t - bm);
  }
  pe = wave_sum(pe);
  __syncthreads();                        // tid0 done reading sRed (loss)
  if ((tid & 63) == 0) sRed[tid >> 6] = pe;
  __syncthreads();
  if (tid == 0) {
    float es = 0.f;
    #pragma unroll
    for (int w = 0; w < 8; ++w) es += sRed[w];
    atomicAdd(&eA[0], es);
    atomicAdd(&eA[2], lblk);
    __threadfence();
    int old = atomicAdd((int*)(eA + 4), 1);
    if (old == (int)gridDim.x - 1) {      // last block: decide
      __threadfence();
      float err = atomicAdd(&eA[0], 0.f);
      float ls  = atomicAdd(&eA[2], 0.f);
      if (err <= 0.005f) { out[0] = 100.f * ls; done[0] = 1; }
      else               { out[0] = 0.f;        done[0] = 0; }
    }
  }
}

// ---- k5: cooperative fallback (iters 2..100 + loss); exits when done -------
__global__ __launch_bounds__(1024)
void k5_fallback(const float* __restrict__ M, float* __restrict__ out,
                 float* __restrict__ v, float* __restrict__ u,
                 const float* __restrict__ tArr, float* __restrict__ eA,
                 const int* __restrict__ done) {
  if (done[0]) return;
  cg::grid_group grid = cg::this_grid();
  const int tid = threadIdx.x, bid = blockIdx.x;
  const float am = 1.0f / NROW, bm = 1.0f / NCOL, EPSV = 1e-16f;

  __shared__ float sU[NROW];
  __shared__ float sCol[16 * 256];
  __shared__ float sRedA[16], sRedB[16];

  const int chunk = tid & 63;
  const int part  = tid >> 6;
  const int col0  = (bid << 8) + (chunk << 2);
  const int r0    = part << 5;
  const int row0  = bid << 1;

  float tt = (tid < 256) ? tArr[(bid << 8) + tid] : 0.f;

  int cpt = 1;
  while (true) {
    if (tid < 256) v[(bid << 8) + tid] = bm / (tt + EPSV);
    grid.sync();
    cpt++;

    {
      const float4* M40 = (const float4*)M + (size_t)row0 * (NCOL / 4);
      const float4* M41 = (const float4*)M + (size_t)(row0 + 1) * (NCOL / 4);
      const float4* V4  = (const float4*)v;
      float ra = 0.f, rb = 0.f;
      #pragma unroll 4
      for (int it = 0; it < NCOL / 4 / 1024; ++it) {
        const int c = (it << 10) + tid;
        float4 vv = V4[c];
        float4 m0 = M40[c], m1 = M41[c];
        ra += __expf(-20.f * m0.x) * vv.x + __expf(-20.f * m0.y) * vv.y
            + __expf(-20.f * m0.z) * vv.z + __expf(-20.f * m0.w) * vv.w;
        rb += __expf(-20.f * m1.x) * vv.x + __expf(-20.f * m1.y) * vv.y
            + __expf(-20.f * m1.z) * vv.z + __expf(-20.f * m1.w) * vv.w;
      }
      ra = wave_sum(ra); rb = wave_sum(rb);
      if ((tid & 63) == 0) { sRedA[tid >> 6] = ra; sRedB[tid >> 6] = rb; }
      __syncthreads();
      if (tid < 2) {
        const float* sr = (tid == 0) ? sRedA : sRedB;
        float s = 0.f;
        #pragma unroll
        for (int w = 0; w < 16; ++w) s += sr[w];
        u[row0 + tid] = am / (s + EPSV);
      }
    }
    grid.sync();
    if (cpt >= 100) break;

    if (tid < NROW) sU[tid] = u[tid];
    __syncthreads();
    float4 cs = {0.f, 0.f, 0.f, 0.f};
    #pragma unroll 4
    for (int r = r0; r < r0 + 32; ++r) {
      float4 m = *(const float4*)(M + (size_t)r * NCOL + col0);
      float us = sU[r];
      cs.x = fmaf(__expf(-20.f * m.x), us, cs.x);
      cs.y = fmaf(__expf(-20.f * m.y), us, cs.y);
      cs.z = fmaf(__expf(-20.f * m.z), us, cs.z);
      cs.w = fmaf(__expf(-20.f * m.w), us, cs.w);
    }
    *(float4*)(sCol + part * 256 + (chunk << 2)) = cs;
    __syncthreads();
    if (tid < 256) {
      tt = 0.f;
      #pragma unroll
      for (int p = 0; p < 16; ++p) tt += sCol[p * 256 + tid];
    }

    if (cpt == 51) {
      float pe = (tid < 256) ? fabsf(v[(bid << 8) + tid] * tt - bm) : 0.f;
      pe = wave_sum(pe);
      __syncthreads();
      if ((tid & 63) == 0) sRedA[tid >> 6] = pe;
      __syncthreads();
      if (tid == 0) {
        float s = 0.f;
        #pragma unroll
        for (int w = 0; w < 16; ++w) s += sRedA[w];
        atomicAdd(&eA[1], s);
      }
      grid.sync();
      if (eA[1] <= 0.005f) break;
    }
  }

  __syncthreads();
  if (tid < NROW) sU[tid] = u[tid];
  __syncthreads();
  {
    const float4 vv = *(const float4*)(v + col0);
    float lacc = 0.f;
    #pragma unroll 4
    for (int r = r0; r < r0 + 32; ++r) {
      float4 m = *(const float4*)(M + (size_t)r * NCOL + col0);
      float us = sU[r];
      lacc += us * (__expf(-20.f * m.x) * m.x * vv.x
                  + __expf(-20.f * m.y) * m.y * vv.y
                  + __expf(-20.f * m.z) * m.z * vv.z
                  + __expf(-20.f * m.w) * m.w * vv.w);
    }
    lacc = wave_sum(lacc);
    if ((tid & 63) == 0) sRedA[tid >> 6] = lacc;
    __syncthreads();
    if (tid == 0) {
      float s = 0.f;
      #pragma unroll
      for (int w = 0; w < 16; ++w) s += sRedA[w];
      atomicAdd(out, 100.f * s);
    }
  }
}

extern "C" void kernel_launch(void* const* d_in, const int* in_sizes, int n_in,
                              void* d_out, int out_size, void* d_ws, size_t ws_size,
                              hipStream_t stream) {
  const float* M = (const float*)d_in[0];
  float* out = (float*)d_out;

  // ws: v | tArr | u | eA(+cnt) | done
  const size_t offV = 0;
  const size_t offT = offV + (size_t)NCOL * sizeof(float);      // 256 KB
  const size_t offU = offT + (size_t)NCOL * sizeof(float);      // 256 KB
  const size_t offE = offU + 4096;
  const size_t offD = offE + 256;
  const size_t need = offD + 256;
  if (ws_size < need) return;

  char* ws = (char*)d_ws;
  float* v    = (float*)(ws + offV);
  float* tArr = (float*)(ws + offT);
  float* u    = (float*)(ws + offU);
  float* eA   = (float*)(ws + offE);
  int*   done = (int*)(ws + offD);

  k1_colsum  <<<dim3(512), dim3(512), 0, stream>>>(M, v, eA);
  k2_rowdot  <<<dim3(512), dim3(512), 0, stream>>>(M, v, u);
  k3_colsum_u<<<dim3(512), dim3(512), 0, stream>>>(M, v, u, tArr, eA, out, done);

  void* args[] = { (void*)&M, (void*)&out, (void*)&v, (void*)&u,
                   (void*)&tArr, (void*)&eA, (void*)&done };
  hipLaunchCooperativeKernel((void*)k5_fallback, dim3(256), dim3(1024),
                             args, 0, stream);
}